// Round 22
// baseline (78.204 us; speedup 1.0000x reference)
//
#include <hip/hip_runtime.h>
#include <hip/hip_bf16.h>

typedef unsigned short u16;
typedef unsigned int u32;
typedef __attribute__((ext_vector_type(8))) short bf16x8;
typedef __attribute__((ext_vector_type(4))) float f32x4;
typedef __attribute__((ext_vector_type(2))) float f32x2;
typedef __attribute__((ext_vector_type(4))) unsigned short u16x4;

#define NBLK 256   // 256 blocks x 512 rows = 131072 rows; 1 block/CU (LDS-capped)

// shared_exp = floor(log2(amax)) - 8 ; scale = 2^shared_exp (power of two)
__device__ __forceinline__ void block_scale(float amax, float& scale, float& inv_scale) {
    int be = (int)(__float_as_uint(amax) >> 23);   // biased exponent, amax >= 0
    be = be < 8 ? 8 : be;                          // tiny/zero blocks quantize to 0 anyway
    scale     = __uint_as_float((unsigned)(be - 8) << 23);   // 2^(be-135)
    inv_scale = __uint_as_float((unsigned)(262 - be) << 23); // 2^(135-be)
}

#if __has_builtin(__builtin_amdgcn_cvt_pk_fp8_f32) && __has_builtin(__builtin_amdgcn_cvt_pk_f32_fp8)
#define HAS_HW_FP8 1
#else
#define HAS_HW_FP8 0
#endif

#if !HAS_HW_FP8
// Fallback: exact bit-math e4m3 RNE (verified in round 0)
__device__ __forceinline__ float mx_e4m3(float x, float inv_scale, float scale) {
    float v  = x * inv_scale;
    float av = fabsf(v);
    int e = (int)(__float_as_uint(av) >> 23) - 127;
    e = e < -6 ? -6 : (e > 8 ? 8 : e);
    float qs = __uint_as_float((unsigned)(130 - e) << 23);
    float qm = __uint_as_float((unsigned)(124 + e) << 23);
    float q  = fminf(rintf(av * qs) * qm, 448.0f);
    return copysignf(q, v) * scale;
}
#endif

// Quantize 4 elems to e4m3 grid (RNE, saturate 448), return bf16 bits of value*scale.
__device__ __forceinline__ u16x4 quant4(float4 v, float inv, float sc) {
    u16x4 r;
#if HAS_HW_FP8
    float a = fminf(fmaxf(v.x * inv, -448.f), 448.f);
    float b = fminf(fmaxf(v.y * inv, -448.f), 448.f);
    float c = fminf(fmaxf(v.z * inv, -448.f), 448.f);
    float d = fminf(fmaxf(v.w * inv, -448.f), 448.f);
    int p = __builtin_amdgcn_cvt_pk_fp8_f32(a, b, 0, false);   // RNE f32->e4m3 (OCP)
    p     = __builtin_amdgcn_cvt_pk_fp8_f32(c, d, p, true);
    f32x2 lo = __builtin_amdgcn_cvt_pk_f32_fp8(p, false);      // exact e4m3->f32
    f32x2 hi = __builtin_amdgcn_cvt_pk_f32_fp8(p, true);
    r.x = (u16)(__float_as_uint(lo[0] * sc) >> 16);
    r.y = (u16)(__float_as_uint(lo[1] * sc) >> 16);
    r.z = (u16)(__float_as_uint(hi[0] * sc) >> 16);
    r.w = (u16)(__float_as_uint(hi[1] * sc) >> 16);
#else
    r.x = (u16)(__float_as_uint(mx_e4m3(v.x, inv, sc)) >> 16);
    r.y = (u16)(__float_as_uint(mx_e4m3(v.y, inv, sc)) >> 16);
    r.z = (u16)(__float_as_uint(mx_e4m3(v.z, inv, sc)) >> 16);
    r.w = (u16)(__float_as_uint(mx_e4m3(v.w, inv, sc)) >> 16);
#endif
    return r;
}

// Quantize 256x256 weight to bf16 fake-quant, stored TRANSPOSED: Bq[n*256+k].
__global__ void wq_kernel(const float* __restrict__ W, u16* __restrict__ Bq) {
    const int t  = blockIdx.x * blockDim.x + threadIdx.x;
    const int f  = t * 4;
    const int k  = f >> 8;
    const int n0 = f & 255;
    const float4 v = *(const float4*)(W + f);
    float am = fmaxf(fmaxf(fabsf(v.x), fabsf(v.y)), fmaxf(fabsf(v.z), fabsf(v.w)));
    am = fmaxf(am, __shfl_xor(am, 1));   // 8 lanes x 4 elems = one 32-elem MX block
    am = fmaxf(am, __shfl_xor(am, 2));
    am = fmaxf(am, __shfl_xor(am, 4));
    float sc, inv; block_scale(am, sc, inv);
    u16x4 q = quant4(v, inv, sc);
    Bq[(size_t)(n0 + 0) * 256 + k] = q.x;
    Bq[(size_t)(n0 + 1) * 256 + k] = q.y;
    Bq[(size_t)(n0 + 2) * 256 + k] = q.z;
    Bq[(size_t)(n0 + 3) * 256 + k] = q.w;
}

// R19 structure at 16 waves/block (4 waves/SIMD) via col-half pairing:
//  - 1 block (1024 thr, 16 waves)/CU; whole B (128 KB, fragment-native
//    [ct][ks][slot], slot=(lg*16+lr)^(ks*9)) + bias in LDS; one __syncthreads.
//  - wave w -> row-group rg=w&7, col-half c=w>>3. 4 strips x 128 rows; per
//    strip each wave: 16 float4 loads of its 16-row tile (pair-wave c=1 reads
//    the SAME rows -> L1/L2 hit, no extra HBM), in-register quant (amax via
//    shfl_xor 16/32 = one 32-elem MX block), MFMA over its 128-col half in two
//    col-quarters (acc[4] live; per-wave live-set = proven xv64+af32 shape).
//  - 4 waves/SIMD (vs 2 in R19) doubles latency hiding in every phase; strip
//    frontier stays 128 rows (R13/R19's proven L2-clean write discipline —
//    fixes R16's 256-row-frontier WRITE amplification).
//  - pure pacing s_barrier between strips (no waitcnt).
__global__ void __launch_bounds__(1024, 1)
mx_gemm(const float* __restrict__ X, const u16* __restrict__ Bq,
        const float* __restrict__ bias, float* __restrict__ out)
{
    __shared__ u16   Bs[256 * 256];   // 128 KB: [ct][ks][slot] 1KB fragment tiles
    __shared__ float bs[256];         // bias
    const int tid = threadIdx.x;
    const int w   = tid >> 6;         // 0..15
    const int rg  = w & 7;            // row-group within strip
    const int c   = w >> 3;           // col half 0/1
    const int l   = tid & 63;
    const int lr  = l & 15;
    const int lg  = l >> 4;
    const size_t rowblk = (size_t)blockIdx.x * 512;

    // ---- one-time prologue: B -> LDS in fragment-native layout; bias -> LDS ----
    #pragma unroll
    for (int i = 0; i < 8; ++i) {
        const u32 g   = (u32)(tid + i * 1024) * 16;    // linear byte offset in Bq
        const u32 n   = g >> 9;                        // output column 0..255
        const u32 kc  = (g >> 4) & 31;                 // ks*4 + lg
        const u32 ks  = kc >> 2;
        const u32 lgd = kc & 3;
        const u32 d   = (n >> 4) * 8192 + ks * 1024
                      + ((((lgd << 4) | (n & 15)) ^ (ks * 9)) << 4);
        *(bf16x8*)((char*)Bs + d) = *(const bf16x8*)((const char*)Bq + g);
    }
    if (tid < 256) bs[tid] = bias[tid];
    __syncthreads();

    const u32   lslot = (u32)(lg * 16 + lr);   // lane id: linear read pattern
    const char* BsB   = (const char*)Bs;

    #pragma unroll 1
    for (int s = 0; s < 4; ++s) {
        const size_t rowt0 = rowblk + (size_t)s * 128 + (size_t)rg * 16;
        const float* xp = X + (rowt0 + lr) * 256 + lg * 8;

        // ---- 16 tile loads, issued back-to-back (16 KB in flight per wave) ----
        float4 xv[16];
        #pragma unroll
        for (int kp = 0; kp < 8; ++kp) {
            xv[2 * kp]     = *(const float4*)(xp + kp * 32);
            xv[2 * kp + 1] = *(const float4*)(xp + kp * 32 + 4);
        }

        // ---- quantize in-register: xv dies into af ----
        bf16x8 af[8];
        #pragma unroll
        for (int ks = 0; ks < 8; ++ks) {
            const float4 v0 = xv[2 * ks], v1 = xv[2 * ks + 1];
            float am = fmaxf(fmaxf(fabsf(v0.x), fabsf(v0.y)), fmaxf(fabsf(v0.z), fabsf(v0.w)));
            am = fmaxf(am, fmaxf(fmaxf(fabsf(v1.x), fabsf(v1.y)), fmaxf(fabsf(v1.z), fabsf(v1.w))));
            am = fmaxf(am, __shfl_xor(am, 16));   // other lg lanes, same row
            am = fmaxf(am, __shfl_xor(am, 32));   // = one 32-elem MX block per row
            float sc, inv; block_scale(am, sc, inv);
            const u16x4 q0 = quant4(v0, inv, sc);
            const u16x4 q1 = quant4(v1, inv, sc);
            bf16x8 a;
            a[0] = (short)q0.x; a[1] = (short)q0.y; a[2] = (short)q0.z; a[3] = (short)q0.w;
            a[4] = (short)q1.x; a[5] = (short)q1.y; a[6] = (short)q1.z; a[7] = (short)q1.w;
            af[ks] = a;
        }

        // ---- MFMA over this wave's 128-col half, two col-quarters ----
        float* op = out + (rowt0 + lr) * 256 + lg * 4;
        #pragma unroll
        for (int h = 0; h < 2; ++h) {
            f32x4 acc[4];
            #pragma unroll
            for (int ct = 0; ct < 4; ++ct) {
                const u32 q = (u32)(c * 8 + h * 4 + ct);      // 16-col tile index
                acc[ct] = *(const f32x4*)(bs + q * 16 + lg * 4);
            }
            #pragma unroll
            for (int ks = 0; ks < 8; ++ks) {
                #pragma unroll
                for (int ct = 0; ct < 4; ++ct) {
                    const u32 q   = (u32)(c * 8 + h * 4 + ct);
                    const u32 off = q * 8192 + (u32)ks * 1024
                                  + ((lslot ^ (u32)(ks * 9)) << 4);
                    const bf16x8 bf = *(const bf16x8*)(BsB + off);
                    acc[ct] = __builtin_amdgcn_mfma_f32_16x16x32_bf16(bf, af[ks], acc[ct], 0, 0, 0);
                }
            }
            #pragma unroll
            for (int ct = 0; ct < 4; ++ct) {
                const u32 q = (u32)(c * 8 + h * 4 + ct);
                *(f32x4*)(op + q * 16) = acc[ct];
            }
        }

        // ---- pure pacing barrier: no waitcnt, loads/stores stay in flight ----
        if (s < 3) __builtin_amdgcn_s_barrier();
    }
}

extern "C" void kernel_launch(void* const* d_in, const int* in_sizes, int n_in,
                              void* d_out, int out_size, void* d_ws, size_t ws_size,
                              hipStream_t stream) {
    const float* x    = (const float*)d_in[0];
    const float* wk   = (const float*)d_in[1];
    const float* bias = (const float*)d_in[2];
    float* out = (float*)d_out;
    u16* Bq    = (u16*)d_ws;                  // 256*256 bf16 = 128 KB scratch
    wq_kernel<<<64, 256, 0, stream>>>(wk, Bq);
    mx_gemm<<<NBLK, 1024, 0, stream>>>(x, Bq, bias, out);
}

// Round 23
// 61.796 us; speedup vs baseline: 1.2655x; 1.2655x over previous
//
#include <hip/hip_runtime.h>
#include <hip/hip_bf16.h>

typedef unsigned short u16;
typedef unsigned int u32;
typedef __attribute__((ext_vector_type(8))) short bf16x8;
typedef __attribute__((ext_vector_type(4))) float f32x4;
typedef __attribute__((ext_vector_type(2))) float f32x2;
typedef __attribute__((ext_vector_type(4))) unsigned short u16x4;

#define NBLK 256   // 256 blocks x 512 rows = 131072 rows; 1 block/CU (LDS-capped)

// shared_exp = floor(log2(amax)) - 8 ; scale = 2^shared_exp (power of two)
__device__ __forceinline__ void block_scale(float amax, float& scale, float& inv_scale) {
    int be = (int)(__float_as_uint(amax) >> 23);   // biased exponent, amax >= 0
    be = be < 8 ? 8 : be;                          // tiny/zero blocks quantize to 0 anyway
    scale     = __uint_as_float((unsigned)(be - 8) << 23);   // 2^(be-135)
    inv_scale = __uint_as_float((unsigned)(262 - be) << 23); // 2^(135-be)
}

#if __has_builtin(__builtin_amdgcn_cvt_pk_fp8_f32) && __has_builtin(__builtin_amdgcn_cvt_pk_f32_fp8)
#define HAS_HW_FP8 1
#else
#define HAS_HW_FP8 0
#endif

#if !HAS_HW_FP8
// Fallback: exact bit-math e4m3 RNE (verified in round 0)
__device__ __forceinline__ float mx_e4m3(float x, float inv_scale, float scale) {
    float v  = x * inv_scale;
    float av = fabsf(v);
    int e = (int)(__float_as_uint(av) >> 23) - 127;
    e = e < -6 ? -6 : (e > 8 ? 8 : e);
    float qs = __uint_as_float((unsigned)(130 - e) << 23);
    float qm = __uint_as_float((unsigned)(124 + e) << 23);
    float q  = fminf(rintf(av * qs) * qm, 448.0f);
    return copysignf(q, v) * scale;
}
#endif

// Quantize 4 elems to e4m3 grid (RNE, saturate 448), return bf16 bits of value*scale.
__device__ __forceinline__ u16x4 quant4(float4 v, float inv, float sc) {
    u16x4 r;
#if HAS_HW_FP8
    float a = fminf(fmaxf(v.x * inv, -448.f), 448.f);
    float b = fminf(fmaxf(v.y * inv, -448.f), 448.f);
    float c = fminf(fmaxf(v.z * inv, -448.f), 448.f);
    float d = fminf(fmaxf(v.w * inv, -448.f), 448.f);
    int p = __builtin_amdgcn_cvt_pk_fp8_f32(a, b, 0, false);   // RNE f32->e4m3 (OCP)
    p     = __builtin_amdgcn_cvt_pk_fp8_f32(c, d, p, true);
    f32x2 lo = __builtin_amdgcn_cvt_pk_f32_fp8(p, false);      // exact e4m3->f32
    f32x2 hi = __builtin_amdgcn_cvt_pk_f32_fp8(p, true);
    r.x = (u16)(__float_as_uint(lo[0] * sc) >> 16);
    r.y = (u16)(__float_as_uint(lo[1] * sc) >> 16);
    r.z = (u16)(__float_as_uint(hi[0] * sc) >> 16);
    r.w = (u16)(__float_as_uint(hi[1] * sc) >> 16);
#else
    r.x = (u16)(__float_as_uint(mx_e4m3(v.x, inv, sc)) >> 16);
    r.y = (u16)(__float_as_uint(mx_e4m3(v.y, inv, sc)) >> 16);
    r.z = (u16)(__float_as_uint(mx_e4m3(v.z, inv, sc)) >> 16);
    r.w = (u16)(__float_as_uint(mx_e4m3(v.w, inv, sc)) >> 16);
#endif
    return r;
}

// Quantize 256x256 weight to bf16 fake-quant, stored TRANSPOSED: Bq[n*256+k].
__global__ void wq_kernel(const float* __restrict__ W, u16* __restrict__ Bq) {
    const int t  = blockIdx.x * blockDim.x + threadIdx.x;
    const int f  = t * 4;
    const int k  = f >> 8;
    const int n0 = f & 255;
    const float4 v = *(const float4*)(W + f);
    float am = fmaxf(fmaxf(fabsf(v.x), fabsf(v.y)), fmaxf(fabsf(v.z), fabsf(v.w)));
    am = fmaxf(am, __shfl_xor(am, 1));   // 8 lanes x 4 elems = one 32-elem MX block
    am = fmaxf(am, __shfl_xor(am, 2));
    am = fmaxf(am, __shfl_xor(am, 4));
    float sc, inv; block_scale(am, sc, inv);
    u16x4 q = quant4(v, inv, sc);
    Bq[(size_t)(n0 + 0) * 256 + k] = q.x;
    Bq[(size_t)(n0 + 1) * 256 + k] = q.y;
    Bq[(size_t)(n0 + 2) * 256 + k] = q.z;
    Bq[(size_t)(n0 + 3) * 256 + k] = q.w;
}

// FINAL (= R19, session best 57.9 us): whole-B-in-LDS, pacing-barrier streaming
// GEMM with halved B-LDS traffic (32 rows per wave per B-sweep).
//  - 1 block (8 waves)/CU; B (128 KB bf16 [n][k]) in fragment-native LDS layout
//    [ct][ks][slot], slot = (lg*16+lr)^(ks*9): reads are the canonical
//    linear-lane ds_read_b128 pattern (conflicts 4.2M -> 786K vs row-swizzle).
//  - 2 strips x 256 rows; per strip each wave quantizes TWO 16-row tiles
//    (xv regs reused serially -> peak ~115 VGPR, under the compiler's ~128 wall);
//    each B-fragment ds_read feeds 2 MFMAs (one per row-tile) -> per-CU LDS
//    traffic halved, strip boundaries halved.
//  - in-register quant: lane lr = row, k = ks*32+lg*8; amax via shfl_xor(16/32)
//    across the 4 lg-lanes of a row = one 32-elem MX block; e4m3 RNE via HW
//    cvt_pk (pre-clamped +-448), bf16 re-encode exact.
//  - pure pacing s_barrier between strips (no waitcnt: Bs read-only, X
//    wave-private, stores unordered) -> loads/stores stay in flight, write
//    frontier stays compact (FETCH 66 MB / WRITE 131 MB, no RMW amplification).
__global__ void __launch_bounds__(512, 1)
mx_gemm(const float* __restrict__ X, const u16* __restrict__ Bq,
        const float* __restrict__ bias, float* __restrict__ out)
{
    __shared__ u16   Bs[256 * 256];   // 128 KB: [ct][ks][slot] 1KB fragment tiles
    __shared__ float bs[256];         // bias
    const int tid = threadIdx.x;
    const int w   = tid >> 6;
    const int l   = tid & 63;
    const int lr  = l & 15;
    const int lg  = l >> 4;
    const size_t rowblk = (size_t)blockIdx.x * 512;

    // ---- one-time prologue: B -> LDS in fragment-native layout; bias -> LDS ----
    #pragma unroll
    for (int i = 0; i < 16; ++i) {
        const u32 g   = (u32)(tid + i * 512) * 16;     // linear byte offset in Bq
        const u32 n   = g >> 9;                        // output column 0..255
        const u32 kc  = (g >> 4) & 31;                 // ks*4 + lg
        const u32 ks  = kc >> 2;
        const u32 lgd = kc & 3;
        const u32 d   = (n >> 4) * 8192 + ks * 1024
                      + ((((lgd << 4) | (n & 15)) ^ (ks * 9)) << 4);
        *(bf16x8*)((char*)Bs + d) = *(const bf16x8*)((const char*)Bq + g);
    }
    if (tid < 256) bs[tid] = bias[tid];
    __syncthreads();

    const u32   lslot = (u32)(lg * 16 + lr);   // lane id: linear read pattern
    const char* BsB   = (const char*)Bs;

    #pragma unroll 1
    for (int s = 0; s < 2; ++s) {
        const size_t rowt0 = rowblk + (size_t)s * 256 + (size_t)w * 16;  // tile 0
        // tile 1 = rowt0 + 128

        bf16x8 af0[8], af1[8];
        #pragma unroll
        for (int half = 0; half < 2; ++half) {
            const float* xp = X + (rowt0 + (size_t)half * 128 + lr) * 256 + lg * 8;
            // ---- 16 tile loads, issued back-to-back ----
            float4 xv[16];
            #pragma unroll
            for (int kp = 0; kp < 8; ++kp) {
                xv[2 * kp]     = *(const float4*)(xp + kp * 32);
                xv[2 * kp + 1] = *(const float4*)(xp + kp * 32 + 4);
            }
            // ---- quantize in-register: xv dies into af ----
            #pragma unroll
            for (int ks = 0; ks < 8; ++ks) {
                const float4 v0 = xv[2 * ks], v1 = xv[2 * ks + 1];
                float am = fmaxf(fmaxf(fabsf(v0.x), fabsf(v0.y)), fmaxf(fabsf(v0.z), fabsf(v0.w)));
                am = fmaxf(am, fmaxf(fmaxf(fabsf(v1.x), fabsf(v1.y)), fmaxf(fabsf(v1.z), fabsf(v1.w))));
                am = fmaxf(am, __shfl_xor(am, 16));   // other lg lanes, same row
                am = fmaxf(am, __shfl_xor(am, 32));   // = one 32-elem MX block per row
                float sc, inv; block_scale(am, sc, inv);
                const u16x4 q0 = quant4(v0, inv, sc);
                const u16x4 q1 = quant4(v1, inv, sc);
                bf16x8 a;
                a[0] = (short)q0.x; a[1] = (short)q0.y; a[2] = (short)q0.z; a[3] = (short)q0.w;
                a[4] = (short)q1.x; a[5] = (short)q1.y; a[6] = (short)q1.z; a[7] = (short)q1.w;
                if (half == 0) af0[ks] = a; else af1[ks] = a;
            }
        }

        // ---- MFMA in four col-quarters; each B ds_read feeds BOTH row-tiles ----
        float* op0 = out + (rowt0 + lr) * 256 + lg * 4;
        float* op1 = op0 + (size_t)128 * 256;
        #pragma unroll
        for (int h = 0; h < 4; ++h) {
            f32x4 acc0[4], acc1[4];
            #pragma unroll
            for (int ct = 0; ct < 4; ++ct) {
                const f32x4 bv = *(const f32x4*)(bs + (h * 4 + ct) * 16 + lg * 4);
                acc0[ct] = bv; acc1[ct] = bv;
            }
            #pragma unroll
            for (int ks = 0; ks < 8; ++ks) {
                #pragma unroll
                for (int ct = 0; ct < 4; ++ct) {
                    const u32 off = (u32)(h * 4 + ct) * 8192 + (u32)ks * 1024
                                  + ((lslot ^ (u32)(ks * 9)) << 4);
                    const bf16x8 bf = *(const bf16x8*)(BsB + off);
                    acc0[ct] = __builtin_amdgcn_mfma_f32_16x16x32_bf16(bf, af0[ks], acc0[ct], 0, 0, 0);
                    acc1[ct] = __builtin_amdgcn_mfma_f32_16x16x32_bf16(bf, af1[ks], acc1[ct], 0, 0, 0);
                }
            }
            #pragma unroll
            for (int ct = 0; ct < 4; ++ct) {
                *(f32x4*)(op0 + (h * 4 + ct) * 16) = acc0[ct];
                *(f32x4*)(op1 + (h * 4 + ct) * 16) = acc1[ct];
            }
        }

        // ---- pure pacing barrier: no waitcnt, loads/stores stay in flight ----
        if (s < 1) __builtin_amdgcn_s_barrier();
    }
}

extern "C" void kernel_launch(void* const* d_in, const int* in_sizes, int n_in,
                              void* d_out, int out_size, void* d_ws, size_t ws_size,
                              hipStream_t stream) {
    const float* x    = (const float*)d_in[0];
    const float* wk   = (const float*)d_in[1];
    const float* bias = (const float*)d_in[2];
    float* out = (float*)d_out;
    u16* Bq    = (u16*)d_ws;                  // 256*256 bf16 = 128 KB scratch
    wq_kernel<<<64, 256, 0, stream>>>(wk, Bq);
    mx_gemm<<<NBLK, 512, 0, stream>>>(x, Bq, bias, out);
}

// Round 24
// 56.424 us; speedup vs baseline: 1.3860x; 1.0952x over previous
//
#include <hip/hip_runtime.h>
#include <hip/hip_bf16.h>

typedef unsigned short u16;
typedef unsigned int u32;
typedef __attribute__((ext_vector_type(8))) short bf16x8;
typedef __attribute__((ext_vector_type(4))) float f32x4;
typedef __attribute__((ext_vector_type(2))) float f32x2;
typedef __attribute__((ext_vector_type(4))) unsigned short u16x4;

#define NBLK 256   // 256 blocks x 512 rows = 131072 rows; 1 block/CU (LDS-capped)

// shared_exp = floor(log2(amax)) - 8 ; scale = 2^shared_exp (power of two)
__device__ __forceinline__ void block_scale(float amax, float& scale, float& inv_scale) {
    int be = (int)(__float_as_uint(amax) >> 23);   // biased exponent, amax >= 0
    be = be < 8 ? 8 : be;                          // tiny/zero blocks quantize to 0 anyway
    scale     = __uint_as_float((unsigned)(be - 8) << 23);   // 2^(be-135)
    inv_scale = __uint_as_float((unsigned)(262 - be) << 23); // 2^(135-be)
}

#if __has_builtin(__builtin_amdgcn_cvt_pk_fp8_f32) && __has_builtin(__builtin_amdgcn_cvt_pk_f32_fp8)
#define HAS_HW_FP8 1
#else
#define HAS_HW_FP8 0
#endif

#if !HAS_HW_FP8
// Fallback: exact bit-math e4m3 RNE (verified in round 0)
__device__ __forceinline__ float mx_e4m3(float x, float inv_scale, float scale) {
    float v  = x * inv_scale;
    float av = fabsf(v);
    int e = (int)(__float_as_uint(av) >> 23) - 127;
    e = e < -6 ? -6 : (e > 8 ? 8 : e);
    float qs = __uint_as_float((unsigned)(130 - e) << 23);
    float qm = __uint_as_float((unsigned)(124 + e) << 23);
    float q  = fminf(rintf(av * qs) * qm, 448.0f);
    return copysignf(q, v) * scale;
}
#endif

// Quantize 4 elems to e4m3 grid (RNE, saturate 448), return bf16 bits of value*scale.
__device__ __forceinline__ u16x4 quant4(float4 v, float inv, float sc) {
    u16x4 r;
#if HAS_HW_FP8
    float a = fminf(fmaxf(v.x * inv, -448.f), 448.f);
    float b = fminf(fmaxf(v.y * inv, -448.f), 448.f);
    float c = fminf(fmaxf(v.z * inv, -448.f), 448.f);
    float d = fminf(fmaxf(v.w * inv, -448.f), 448.f);
    int p = __builtin_amdgcn_cvt_pk_fp8_f32(a, b, 0, false);   // RNE f32->e4m3 (OCP)
    p     = __builtin_amdgcn_cvt_pk_fp8_f32(c, d, p, true);
    f32x2 lo = __builtin_amdgcn_cvt_pk_f32_fp8(p, false);      // exact e4m3->f32
    f32x2 hi = __builtin_amdgcn_cvt_pk_f32_fp8(p, true);
    r.x = (u16)(__float_as_uint(lo[0] * sc) >> 16);
    r.y = (u16)(__float_as_uint(lo[1] * sc) >> 16);
    r.z = (u16)(__float_as_uint(hi[0] * sc) >> 16);
    r.w = (u16)(__float_as_uint(hi[1] * sc) >> 16);
#else
    r.x = (u16)(__float_as_uint(mx_e4m3(v.x, inv, sc)) >> 16);
    r.y = (u16)(__float_as_uint(mx_e4m3(v.y, inv, sc)) >> 16);
    r.z = (u16)(__float_as_uint(mx_e4m3(v.z, inv, sc)) >> 16);
    r.w = (u16)(__float_as_uint(mx_e4m3(v.w, inv, sc)) >> 16);
#endif
    return r;
}

// Quantize 256x256 weight to bf16 fake-quant, stored TRANSPOSED: Bq[n*256+k].
__global__ void wq_kernel(const float* __restrict__ W, u16* __restrict__ Bq) {
    const int t  = blockIdx.x * blockDim.x + threadIdx.x;
    const int f  = t * 4;
    const int k  = f >> 8;
    const int n0 = f & 255;
    const float4 v = *(const float4*)(W + f);
    float am = fmaxf(fmaxf(fabsf(v.x), fabsf(v.y)), fmaxf(fabsf(v.z), fabsf(v.w)));
    am = fmaxf(am, __shfl_xor(am, 1));   // 8 lanes x 4 elems = one 32-elem MX block
    am = fmaxf(am, __shfl_xor(am, 2));
    am = fmaxf(am, __shfl_xor(am, 4));
    float sc, inv; block_scale(am, sc, inv);
    u16x4 q = quant4(v, inv, sc);
    Bq[(size_t)(n0 + 0) * 256 + k] = q.x;
    Bq[(size_t)(n0 + 1) * 256 + k] = q.y;
    Bq[(size_t)(n0 + 2) * 256 + k] = q.z;
    Bq[(size_t)(n0 + 3) * 256 + k] = q.w;
}

// R19 + cross-phase prefetch, VGPR budget unpinned via amdgpu_waves_per_eu(2,2):
//  - the CU is LDS-capped at 1 block = 8 waves = 2 waves/EU anyway, so pinning
//    waves-per-eu to (2,2) changes nothing physically but raises the register
//    allocator's per-wave budget from its 4-waves/EU default (128) to 256.
//  - strip 0 issues strip 1's FIRST 16-row tile loads into xvN[16] (64 VGPRs)
//    before the MFMA phase; they stay in flight across the entire MFMA phase
//    (T14) -> strip 1's drain is half-hidden. Live peak during MFMA ~190 regs.
//  - everything else IDENTICAL to R19 (session best 57.9 us): whole B in
//    fragment-native LDS, 2 strips x 256 rows, 2-tile B-sweep amortization,
//    in-register quant, four col-quarters (acc[4]x2 live), pacing s_barrier.
__global__ void __launch_bounds__(512)
__attribute__((amdgpu_waves_per_eu(2, 2)))
mx_gemm(const float* __restrict__ X, const u16* __restrict__ Bq,
        const float* __restrict__ bias, float* __restrict__ out)
{
    __shared__ u16   Bs[256 * 256];   // 128 KB: [ct][ks][slot] 1KB fragment tiles
    __shared__ float bs[256];         // bias
    const int tid = threadIdx.x;
    const int w   = tid >> 6;
    const int l   = tid & 63;
    const int lr  = l & 15;
    const int lg  = l >> 4;
    const size_t rowblk = (size_t)blockIdx.x * 512;

    // ---- one-time prologue: B -> LDS in fragment-native layout; bias -> LDS ----
    #pragma unroll
    for (int i = 0; i < 16; ++i) {
        const u32 g   = (u32)(tid + i * 512) * 16;     // linear byte offset in Bq
        const u32 n   = g >> 9;                        // output column 0..255
        const u32 kc  = (g >> 4) & 31;                 // ks*4 + lg
        const u32 ks  = kc >> 2;
        const u32 lgd = kc & 3;
        const u32 d   = (n >> 4) * 8192 + ks * 1024
                      + ((((lgd << 4) | (n & 15)) ^ (ks * 9)) << 4);
        *(bf16x8*)((char*)Bs + d) = *(const bf16x8*)((const char*)Bq + g);
    }
    if (tid < 256) bs[tid] = bias[tid];
    __syncthreads();

    const u32   lslot = (u32)(lg * 16 + lr);   // lane id: linear read pattern
    const char* BsB   = (const char*)Bs;

    float4 xvN[16];   // prefetch buffer: next strip's tile 0 (held across MFMA)

    #pragma unroll 1
    for (int s = 0; s < 2; ++s) {
        const size_t rowt0 = rowblk + (size_t)s * 256 + (size_t)w * 16;  // tile 0
        // tile 1 = rowt0 + 128

        bf16x8 af0[8], af1[8];

        // ---- tile 0 -> af0: from fresh loads (s=0) or the prefetch (s=1) ----
        if (s == 0) {
            const float* xp = X + (rowt0 + lr) * 256 + lg * 8;
            float4 xv[16];
            #pragma unroll
            for (int kp = 0; kp < 8; ++kp) {
                xv[2 * kp]     = *(const float4*)(xp + kp * 32);
                xv[2 * kp + 1] = *(const float4*)(xp + kp * 32 + 4);
            }
            #pragma unroll
            for (int ks = 0; ks < 8; ++ks) {
                const float4 v0 = xv[2 * ks], v1 = xv[2 * ks + 1];
                float am = fmaxf(fmaxf(fabsf(v0.x), fabsf(v0.y)), fmaxf(fabsf(v0.z), fabsf(v0.w)));
                am = fmaxf(am, fmaxf(fmaxf(fabsf(v1.x), fabsf(v1.y)), fmaxf(fabsf(v1.z), fabsf(v1.w))));
                am = fmaxf(am, __shfl_xor(am, 16));   // other lg lanes, same row
                am = fmaxf(am, __shfl_xor(am, 32));   // = one 32-elem MX block per row
                float sc, inv; block_scale(am, sc, inv);
                const u16x4 q0 = quant4(v0, inv, sc);
                const u16x4 q1 = quant4(v1, inv, sc);
                bf16x8 a;
                a[0] = (short)q0.x; a[1] = (short)q0.y; a[2] = (short)q0.z; a[3] = (short)q0.w;
                a[4] = (short)q1.x; a[5] = (short)q1.y; a[6] = (short)q1.z; a[7] = (short)q1.w;
                af0[ks] = a;
            }
        } else {
            #pragma unroll
            for (int ks = 0; ks < 8; ++ks) {
                const float4 v0 = xvN[2 * ks], v1 = xvN[2 * ks + 1];
                float am = fmaxf(fmaxf(fabsf(v0.x), fabsf(v0.y)), fmaxf(fabsf(v0.z), fabsf(v0.w)));
                am = fmaxf(am, fmaxf(fmaxf(fabsf(v1.x), fabsf(v1.y)), fmaxf(fabsf(v1.z), fabsf(v1.w))));
                am = fmaxf(am, __shfl_xor(am, 16));
                am = fmaxf(am, __shfl_xor(am, 32));
                float sc, inv; block_scale(am, sc, inv);
                const u16x4 q0 = quant4(v0, inv, sc);
                const u16x4 q1 = quant4(v1, inv, sc);
                bf16x8 a;
                a[0] = (short)q0.x; a[1] = (short)q0.y; a[2] = (short)q0.z; a[3] = (short)q0.w;
                a[4] = (short)q1.x; a[5] = (short)q1.y; a[6] = (short)q1.z; a[7] = (short)q1.w;
                af0[ks] = a;
            }
        }

        // ---- tile 1 loads; then (s=0) issue NEXT-strip tile-0 prefetch ----
        {
            const float* xp = X + (rowt0 + 128 + lr) * 256 + lg * 8;
            float4 xv[16];
            #pragma unroll
            for (int kp = 0; kp < 8; ++kp) {
                xv[2 * kp]     = *(const float4*)(xp + kp * 32);
                xv[2 * kp + 1] = *(const float4*)(xp + kp * 32 + 4);
            }
            if (s == 0) {
                const float* xn = X + (rowblk + 256 + (size_t)w * 16 + lr) * 256 + lg * 8;
                #pragma unroll
                for (int kp = 0; kp < 8; ++kp) {
                    xvN[2 * kp]     = *(const float4*)(xn + kp * 32);
                    xvN[2 * kp + 1] = *(const float4*)(xn + kp * 32 + 4);
                }
            }
            __builtin_amdgcn_sched_barrier(0);   // pin prefetch issue here
            #pragma unroll
            for (int ks = 0; ks < 8; ++ks) {
                const float4 v0 = xv[2 * ks], v1 = xv[2 * ks + 1];
                float am = fmaxf(fmaxf(fabsf(v0.x), fabsf(v0.y)), fmaxf(fabsf(v0.z), fabsf(v0.w)));
                am = fmaxf(am, fmaxf(fmaxf(fabsf(v1.x), fabsf(v1.y)), fmaxf(fabsf(v1.z), fabsf(v1.w))));
                am = fmaxf(am, __shfl_xor(am, 16));
                am = fmaxf(am, __shfl_xor(am, 32));
                float sc, inv; block_scale(am, sc, inv);
                const u16x4 q0 = quant4(v0, inv, sc);
                const u16x4 q1 = quant4(v1, inv, sc);
                bf16x8 a;
                a[0] = (short)q0.x; a[1] = (short)q0.y; a[2] = (short)q0.z; a[3] = (short)q0.w;
                a[4] = (short)q1.x; a[5] = (short)q1.y; a[6] = (short)q1.z; a[7] = (short)q1.w;
                af1[ks] = a;
            }
        }
        __builtin_amdgcn_sched_barrier(0);   // keep MFMA phase below

        // ---- MFMA in four col-quarters; each B ds_read feeds BOTH row-tiles ----
        float* op0 = out + (rowt0 + lr) * 256 + lg * 4;
        float* op1 = op0 + (size_t)128 * 256;
        #pragma unroll
        for (int h = 0; h < 4; ++h) {
            f32x4 acc0[4], acc1[4];
            #pragma unroll
            for (int ct = 0; ct < 4; ++ct) {
                const f32x4 bv = *(const f32x4*)(bs + (h * 4 + ct) * 16 + lg * 4);
                acc0[ct] = bv; acc1[ct] = bv;
            }
            #pragma unroll
            for (int ks = 0; ks < 8; ++ks) {
                #pragma unroll
                for (int ct = 0; ct < 4; ++ct) {
                    const u32 off = (u32)(h * 4 + ct) * 8192 + (u32)ks * 1024
                                  + ((lslot ^ (u32)(ks * 9)) << 4);
                    const bf16x8 bf = *(const bf16x8*)(BsB + off);
                    acc0[ct] = __builtin_amdgcn_mfma_f32_16x16x32_bf16(bf, af0[ks], acc0[ct], 0, 0, 0);
                    acc1[ct] = __builtin_amdgcn_mfma_f32_16x16x32_bf16(bf, af1[ks], acc1[ct], 0, 0, 0);
                }
            }
            #pragma unroll
            for (int ct = 0; ct < 4; ++ct) {
                *(f32x4*)(op0 + (h * 4 + ct) * 16) = acc0[ct];
                *(f32x4*)(op1 + (h * 4 + ct) * 16) = acc1[ct];
            }
        }

        // ---- pure pacing barrier: no waitcnt, prefetch stays in flight ----
        if (s < 1) __builtin_amdgcn_s_barrier();
    }
}

extern "C" void kernel_launch(void* const* d_in, const int* in_sizes, int n_in,
                              void* d_out, int out_size, void* d_ws, size_t ws_size,
                              hipStream_t stream) {
    const float* x    = (const float*)d_in[0];
    const float* wk   = (const float*)d_in[1];
    const float* bias = (const float*)d_in[2];
    float* out = (float*)d_out;
    u16* Bq    = (u16*)d_ws;                  // 256*256 bf16 = 128 KB scratch
    wq_kernel<<<64, 256, 0, stream>>>(wk, Bq);
    mx_gemm<<<NBLK, 512, 0, stream>>>(x, Bq, bias, out);
}